// Round 18
// baseline (80.575 us; speedup 1.0000x reference)
//
#include <hip/hip_runtime.h>
#include <hip/hip_bf16.h>
#include <hip/hip_fp16.h>

#define N_NODES 100000
#define N_EDGES 1600000
#define HEADS 8
#define NH (N_NODES * HEADS)    // 800000
#define ALPHA 0.2f

#define BSHIFT 7
#define BSIZE 128               // dst nodes per bucket
#define NBUCK 782               // ceil(100000 / 128)
#define EPB 8192                // edges per scatter block (R18: 2x, no LDS staging)
#define NEB 196                 // ceil(1600000 / 8192)
#define GPROJ 782               // ceil(800000 / 1024) proj blocks (1024 thr)
#define CAP 3072                // fixed slots per bucket (mean 2046, max~2200 @ key=0)
#define RPT 6                   // CAP / 512 records per thread

typedef float floatx4 __attribute__((ext_vector_type(4)));

__device__ __forceinline__ float lrelu(float s) {
    return s >= 0.0f ? s : ALPHA * s;
}

// bf16 helpers (rd needs fp32 EXPONENT range: denom ~1e7 -> rd ~1e-7, which
// underflows fp16 subnormals -- the R12 failure -- but is a normal bf16).
__device__ __forceinline__ unsigned short f2bf(float f) {
    unsigned u = __float_as_uint(f);
    u += 0x7FFFu + ((u >> 16) & 1u);      // round-to-nearest-even
    return (unsigned short)(u >> 16);
}
__device__ __forceinline__ float bf2f(unsigned short s) {
    return __uint_as_float((unsigned)s << 16);
}

// Tables:
//   p1h[n*8+h]  : fp16 src-projection (range +-~16: fp16-safe)
//   prh[n*16+*] : 32-byte record = {fp16 p2[8] | bf16 rd[8]} -- one 32 B
//                 granule serves BOTH dst-indexed gathers in norm.
// R18: scatter drops LDS edge staging (re-reads L2-hot edge in pass 2),
// doubling EPB to 8192 -> 2x fewer bucket atomics, 2x longer write bursts.
// denom's 128-entry scan is now a single-wave shfl scan (12 fewer barriers).

// Kernel 1 (fused): blocks [0, GPROJ) project; blocks [GPROJ, +NEB) scatter
// 4-byte records (src<<7 | dst_local) into fixed-capacity bucket regions.
__global__ __launch_bounds__(1024) void proj_scatter_kernel(
        const float* __restrict__ x, const float* __restrict__ a,
        const int* __restrict__ edge,
        __half* __restrict__ p1h, __half* __restrict__ prh,
        unsigned* __restrict__ gcur, unsigned* __restrict__ sorted) {
    __shared__ unsigned lh[NBUCK];
    __shared__ unsigned lbase[NBUCK];
    int tid = threadIdx.x;
    if (blockIdx.x < GPROJ) {
        int t = blockIdx.x * 1024 + tid;
        if (t >= NH) return;
        int hd = t & 7;
        int n  = t >> 3;
        const float4* xp  = (const float4*)(x + (size_t)n * 128 + hd * 16);
        const float4* a1p = (const float4*)(a);
        const float4* a2p = (const float4*)(a + 16);
        float s1 = 0.f, s2 = 0.f;
#pragma unroll
        for (int i = 0; i < 4; ++i) {
            float4 xv = xp[i];
            float4 v1 = a1p[i];
            float4 v2 = a2p[i];
            s1 += xv.x * v1.x + xv.y * v1.y + xv.z * v1.z + xv.w * v1.w;
            s2 += xv.x * v2.x + xv.y * v2.y + xv.z * v2.z + xv.w * v2.w;
        }
        p1h[t] = __float2half_rn(s1);
        prh[(size_t)n * 16 + hd] = __float2half_rn(s2);
    } else {
        int base = (blockIdx.x - GPROJ) * EPB;
        for (int i = tid; i < NBUCK; i += 1024) lh[i] = 0;
        __syncthreads();
#pragma unroll
        for (int k = 0; k < EPB / 1024; ++k) {
            int e = base + k * 1024 + tid;
            if (e < N_EDGES)
                atomicAdd(&lh[(unsigned)edge[N_EDGES + e] >> BSHIFT], 1u);
        }
        __syncthreads();
        for (int i = tid; i < NBUCK; i += 1024) {
            unsigned c = lh[i];
            lbase[i] = c ? (unsigned)i * CAP + atomicAdd(&gcur[i], c) : 0u;
            lh[i] = 0;   // reuse as local cursor
        }
        __syncthreads();
#pragma unroll
        for (int k = 0; k < EPB / 1024; ++k) {
            int e = base + k * 1024 + tid;
            if (e < N_EDGES) {
                int s = edge[e];                         // L2-hot re-read
                int d = edge[N_EDGES + e];
                unsigned b = (unsigned)d >> BSHIFT;
                unsigned pos = lbase[b] + atomicAdd(&lh[b], 1u);
                sorted[pos] = ((unsigned)s << BSHIFT) | (unsigned)(d & (BSIZE - 1));
            }
        }
    }
}

// Kernel 2: one block per bucket, no float atomics. Counting-sort the bucket's
// records by dst_local in LDS (single chunk: region capacity == CAP); each
// thread owns (dl, head-pair) and serially accumulates its dst's edges in
// fp32 registers. Writes bf16 reciprocal denominators into prh's rd-half.
__global__ __launch_bounds__(512) void denom_kernel(const unsigned* __restrict__ sorted,
                                                    const unsigned* __restrict__ gcur,
                                                    const __half* __restrict__ p1h,
                                                    __half* __restrict__ prh) {
    __shared__ unsigned lsrc[CAP];     // 12 KB sorted-by-dl src indices
    __shared__ unsigned lh[BSIZE];     // per-dl count
    __shared__ unsigned lst[BSIZE];    // per-dl start
    __shared__ unsigned lcur[BSIZE];   // per-dl cursor
    int t = threadIdx.x;
    int b = blockIdx.x;
    int dl = t >> 2;                   // 0..127: owned dst-local
    int hp = t & 3;                    // 0..3: owned head pair (2*hp, 2*hp+1)
    size_t node = (size_t)b * BSIZE + dl;
    bool valid = node < N_NODES;
    float p2a = 0.f, p2b = 0.f;
    if (valid) {
        float2 pv = __half22float2(*(const __half2*)(prh + node * 16 + hp * 2));
        p2a = pv.x; p2b = pv.y;
    }
    unsigned cs  = (unsigned)b * CAP;
    unsigned cnt = min(gcur[b], (unsigned)CAP);

    if (t < BSIZE) lh[t] = 0;
    __syncthreads();
    unsigned recs[RPT];
#pragma unroll
    for (int k = 0; k < RPT; ++k) {
        unsigned i = (unsigned)t + (unsigned)k * 512u;
        bool v = i < cnt;
        recs[k] = v ? sorted[cs + i] : 0xFFFFFFFFu;
        if (v) atomicAdd(&lh[recs[k] & (BSIZE - 1)], 1u);
    }
    __syncthreads();
    // single-wave exclusive scan of 128 counts (lane l owns 2l, 2l+1)
    if (t < 64) {
        unsigned c0 = lh[2 * t], c1 = lh[2 * t + 1];
        unsigned ps = c0 + c1;
        unsigned s = ps;
#pragma unroll
        for (int d = 1; d < 64; d <<= 1) {
            unsigned v = __shfl_up(s, d, 64);
            if (t >= d) s += v;
        }
        unsigned ex = s - ps;                 // exclusive at pair granularity
        lst[2 * t] = ex;          lcur[2 * t] = ex;
        lst[2 * t + 1] = ex + c0; lcur[2 * t + 1] = ex + c0;
    }
    __syncthreads();
#pragma unroll
    for (int k = 0; k < RPT; ++k) {
        unsigned r = recs[k];
        if (r != 0xFFFFFFFFu) {
            unsigned d = r & (BSIZE - 1);
            unsigned pos = atomicAdd(&lcur[d], 1u);
            lsrc[pos] = r >> BSHIFT;
        }
    }
    __syncthreads();
    float acc0 = 0.f, acc1 = 0.f;
    unsigned e0 = lst[dl], e1 = lst[dl] + lh[dl];
    for (unsigned k = e0; k < e1; ++k) {
        unsigned src = lsrc[k];                       // broadcast to 4 lanes
        float2 pv = __half22float2(*(const __half2*)(p1h + (size_t)src * 8 + hp * 2));
        acc0 += __expf(lrelu(pv.x + p2a));
        acc1 += __expf(lrelu(pv.y + p2b));
    }
    if (valid) {
        unsigned short r0 = f2bf(1.0f / (acc0 + 1e-16f));
        unsigned short r1 = f2bf(1.0f / (acc1 + 1e-16f));
        // rd-half of prh (4-byte aligned: byte offset node*32 + 16 + hp*4)
        *(unsigned*)((unsigned short*)prh + node * 16 + 8 + hp * 2) =
            ((unsigned)r1 << 16) | r0;
    }
}

// Kernel 3: edges in ORIGINAL order -> coalesced edge reads and out writes.
// Per edge: p1h[src] (16 B fp16) + prh[dst] (32 B, fp16 p2 + bf16 rd).
// Grid is exactly 6250 blocks (1.6M/256): no bounds check.
__global__ __launch_bounds__(256) void norm_kernel(const int* __restrict__ edge,
                                                   const __half* __restrict__ p1h,
                                                   const __half* __restrict__ prh,
                                                   float* __restrict__ out) {
    int e = blockIdx.x * 256 + threadIdx.x;
    int src = edge[e];
    int dst = edge[N_EDGES + e];
    float4 pv = *(const float4*)(p1h + (size_t)src * 8);       // 8 fp16 p1
    float4 qa = *(const float4*)(prh + (size_t)dst * 16);      // 8 fp16 p2
    float4 qb = *(const float4*)(prh + (size_t)dst * 16 + 8);  // 8 bf16 rd
    const __half2* s1p = (const __half2*)&pv;
    const __half2* s2p = (const __half2*)&qa;
    const unsigned short* rdu = (const unsigned short*)&qb;
    floatx4 o0, o1;
    float ov[8];
#pragma unroll
    for (int k = 0; k < 4; ++k) {
        float2 f1 = __half22float2(s1p[k]);
        float2 f2 = __half22float2(s2p[k]);
        ov[2 * k]     = __expf(lrelu(f1.x + f2.x)) * bf2f(rdu[2 * k]);
        ov[2 * k + 1] = __expf(lrelu(f1.y + f2.y)) * bf2f(rdu[2 * k + 1]);
    }
    o0.x = ov[0]; o0.y = ov[1]; o0.z = ov[2]; o0.w = ov[3];
    o1.x = ov[4]; o1.y = ov[5]; o1.z = ov[6]; o1.w = ov[7];
    floatx4* op = (floatx4*)(out + (size_t)e * 8);
    __builtin_nontemporal_store(o0, op);
    __builtin_nontemporal_store(o1, op + 1);
}

extern "C" void kernel_launch(void* const* d_in, const int* in_sizes, int n_in,
                              void* d_out, int out_size, void* d_ws, size_t ws_size,
                              hipStream_t stream) {
    const float* x    = (const float*)d_in[0];
    const float* a    = (const float*)d_in[1];
    const int*   edge = (const int*)d_in[2];
    float* out = (float*)d_out;

    // Workspace layout (~14.5 MB):
    unsigned* sorted = (unsigned*)d_ws;                              // 9.6 MB (NBUCK*CAP)
    __half*   p1h    = (__half*)(sorted + (size_t)NBUCK * CAP);      // 1.6 MB
    __half*   prh    = p1h + NH;                                     // 3.2 MB (p2+rd)
    unsigned* gcur   = (unsigned*)(prh + (size_t)N_NODES * 16);      // 782

    (void)hipMemsetAsync(gcur, 0, NBUCK * sizeof(unsigned), stream);

    proj_scatter_kernel<<<GPROJ + NEB, 1024, 0, stream>>>(x, a, edge, p1h, prh,
                                                          gcur, sorted);
    denom_kernel<<<NBUCK, 512, 0, stream>>>(sorted, gcur, p1h, prh);
    norm_kernel<<<N_EDGES / 256, 256, 0, stream>>>(edge, p1h, prh, out);
}

// Round 19
// 77.436 us; speedup vs baseline: 1.0405x; 1.0405x over previous
//
#include <hip/hip_runtime.h>
#include <hip/hip_bf16.h>
#include <hip/hip_fp16.h>

#define N_NODES 100000
#define N_EDGES 1600000
#define HEADS 8
#define NH (N_NODES * HEADS)    // 800000
#define ALPHA 0.2f

#define BSHIFT 7
#define BSIZE 128               // dst nodes per bucket
#define NBUCK 782               // ceil(100000 / 128)
#define EPB 4096                // edges per scatter block (staged in LDS -- R18's
                                // unstaged EPB=8192 regressed: proj's 51 MB x-stream
                                // evicts edge from L2 between scatter passes)
#define NEB 391                 // ceil(1600000 / 4096)
#define GPROJ 782               // ceil(800000 / 1024) proj blocks (1024 thr)
#define CAP 3072                // fixed slots per bucket (mean 2046, max~2200 @ key=0)
#define RPT 6                   // CAP / 512 records per thread

typedef float floatx4 __attribute__((ext_vector_type(4)));

__device__ __forceinline__ float lrelu(float s) {
    return s >= 0.0f ? s : ALPHA * s;
}

// bf16 helpers (rd needs fp32 EXPONENT range: denom ~1e7 -> rd ~1e-7, which
// underflows fp16 subnormals -- the R12 failure -- but is a normal bf16).
__device__ __forceinline__ unsigned short f2bf(float f) {
    unsigned u = __float_as_uint(f);
    u += 0x7FFFu + ((u >> 16) & 1u);      // round-to-nearest-even
    return (unsigned short)(u >> 16);
}
__device__ __forceinline__ float bf2f(unsigned short s) {
    return __uint_as_float((unsigned)s << 16);
}

// Tables:
//   p1h[n*8+h]  : fp16 src-projection (range +-~16: fp16-safe)
//   prh[n*16+*] : 32-byte record = {fp16 p2[8] | bf16 rd[8]} -- one 32 B
//                 granule serves BOTH dst-indexed gathers in norm.
// Structure (R19 = R17 + denom shfl-scan): fixed CAP-slot bucket regions,
// no histogram/scan kernels; proj+scatter fused; denom ownership-accumulate;
// norm in original eid order.

// Kernel 1 (fused): blocks [0, GPROJ) project; blocks [GPROJ, +NEB) scatter
// 4-byte records (src<<7 | dst_local) into fixed-capacity bucket regions.
__global__ __launch_bounds__(1024) void proj_scatter_kernel(
        const float* __restrict__ x, const float* __restrict__ a,
        const int* __restrict__ edge,
        __half* __restrict__ p1h, __half* __restrict__ prh,
        unsigned* __restrict__ gcur, unsigned* __restrict__ sorted) {
    __shared__ int lsrc[EPB];
    __shared__ int ldst[EPB];
    __shared__ unsigned lh[NBUCK];
    __shared__ unsigned lbase[NBUCK];
    int tid = threadIdx.x;
    if (blockIdx.x < GPROJ) {
        int t = blockIdx.x * 1024 + tid;
        if (t >= NH) return;
        int hd = t & 7;
        int n  = t >> 3;
        const float4* xp  = (const float4*)(x + (size_t)n * 128 + hd * 16);
        const float4* a1p = (const float4*)(a);
        const float4* a2p = (const float4*)(a + 16);
        float s1 = 0.f, s2 = 0.f;
#pragma unroll
        for (int i = 0; i < 4; ++i) {
            float4 xv = xp[i];
            float4 v1 = a1p[i];
            float4 v2 = a2p[i];
            s1 += xv.x * v1.x + xv.y * v1.y + xv.z * v1.z + xv.w * v1.w;
            s2 += xv.x * v2.x + xv.y * v2.y + xv.z * v2.z + xv.w * v2.w;
        }
        p1h[t] = __float2half_rn(s1);
        prh[(size_t)n * 16 + hd] = __float2half_rn(s2);
    } else {
        int base = (blockIdx.x - GPROJ) * EPB;
        for (int i = tid; i < NBUCK; i += 1024) lh[i] = 0;
        __syncthreads();
#pragma unroll
        for (int k = 0; k < EPB / 1024; ++k) {
            int i = k * 1024 + tid, e = base + i;
            if (e < N_EDGES) {
                lsrc[i] = edge[e];
                int d = edge[N_EDGES + e];
                ldst[i] = d;
                atomicAdd(&lh[(unsigned)d >> BSHIFT], 1u);
            }
        }
        __syncthreads();
        for (int i = tid; i < NBUCK; i += 1024) {
            unsigned c = lh[i];
            lbase[i] = c ? (unsigned)i * CAP + atomicAdd(&gcur[i], c) : 0u;
            lh[i] = 0;   // reuse as local cursor
        }
        __syncthreads();
#pragma unroll
        for (int k = 0; k < EPB / 1024; ++k) {
            int i = k * 1024 + tid, e = base + i;
            if (e < N_EDGES) {
                int d = ldst[i];
                unsigned b = (unsigned)d >> BSHIFT;
                unsigned pos = lbase[b] + atomicAdd(&lh[b], 1u);
                sorted[pos] = ((unsigned)lsrc[i] << BSHIFT) | (unsigned)(d & (BSIZE - 1));
            }
        }
    }
}

// Kernel 2: one block per bucket, no float atomics. Counting-sort the bucket's
// records by dst_local in LDS (single chunk: region capacity == CAP); each
// thread owns (dl, head-pair) and serially accumulates its dst's edges in
// fp32 registers. Writes bf16 reciprocal denominators into prh's rd-half.
__global__ __launch_bounds__(512) void denom_kernel(const unsigned* __restrict__ sorted,
                                                    const unsigned* __restrict__ gcur,
                                                    const __half* __restrict__ p1h,
                                                    __half* __restrict__ prh) {
    __shared__ unsigned lsrc[CAP];     // 12 KB sorted-by-dl src indices
    __shared__ unsigned lh[BSIZE];     // per-dl count
    __shared__ unsigned lst[BSIZE];    // per-dl start
    __shared__ unsigned lcur[BSIZE];   // per-dl cursor
    int t = threadIdx.x;
    int b = blockIdx.x;
    int dl = t >> 2;                   // 0..127: owned dst-local
    int hp = t & 3;                    // 0..3: owned head pair (2*hp, 2*hp+1)
    size_t node = (size_t)b * BSIZE + dl;
    bool valid = node < N_NODES;
    float p2a = 0.f, p2b = 0.f;
    if (valid) {
        float2 pv = __half22float2(*(const __half2*)(prh + node * 16 + hp * 2));
        p2a = pv.x; p2b = pv.y;
    }
    unsigned cs  = (unsigned)b * CAP;
    unsigned cnt = min(gcur[b], (unsigned)CAP);

    if (t < BSIZE) lh[t] = 0;
    __syncthreads();
    unsigned recs[RPT];
#pragma unroll
    for (int k = 0; k < RPT; ++k) {
        unsigned i = (unsigned)t + (unsigned)k * 512u;
        bool v = i < cnt;
        recs[k] = v ? sorted[cs + i] : 0xFFFFFFFFu;
        if (v) atomicAdd(&lh[recs[k] & (BSIZE - 1)], 1u);
    }
    __syncthreads();
    // single-wave exclusive scan of 128 counts (lane l owns 2l, 2l+1)
    if (t < 64) {
        unsigned c0 = lh[2 * t], c1 = lh[2 * t + 1];
        unsigned ps = c0 + c1;
        unsigned s = ps;
#pragma unroll
        for (int d = 1; d < 64; d <<= 1) {
            unsigned v = __shfl_up(s, d, 64);
            if (t >= d) s += v;
        }
        unsigned ex = s - ps;                 // exclusive at pair granularity
        lst[2 * t] = ex;          lcur[2 * t] = ex;
        lst[2 * t + 1] = ex + c0; lcur[2 * t + 1] = ex + c0;
    }
    __syncthreads();
#pragma unroll
    for (int k = 0; k < RPT; ++k) {
        unsigned r = recs[k];
        if (r != 0xFFFFFFFFu) {
            unsigned d = r & (BSIZE - 1);
            unsigned pos = atomicAdd(&lcur[d], 1u);
            lsrc[pos] = r >> BSHIFT;
        }
    }
    __syncthreads();
    float acc0 = 0.f, acc1 = 0.f;
    unsigned e0 = lst[dl], e1 = lst[dl] + lh[dl];
    for (unsigned k = e0; k < e1; ++k) {
        unsigned src = lsrc[k];                       // broadcast to 4 lanes
        float2 pv = __half22float2(*(const __half2*)(p1h + (size_t)src * 8 + hp * 2));
        acc0 += __expf(lrelu(pv.x + p2a));
        acc1 += __expf(lrelu(pv.y + p2b));
    }
    if (valid) {
        unsigned short r0 = f2bf(1.0f / (acc0 + 1e-16f));
        unsigned short r1 = f2bf(1.0f / (acc1 + 1e-16f));
        // rd-half of prh (4-byte aligned: byte offset node*32 + 16 + hp*4)
        *(unsigned*)((unsigned short*)prh + node * 16 + 8 + hp * 2) =
            ((unsigned)r1 << 16) | r0;
    }
}

// Kernel 3: edges in ORIGINAL order -> coalesced edge reads and out writes.
// Per edge: p1h[src] (16 B fp16) + prh[dst] (32 B, fp16 p2 + bf16 rd).
// Grid is exactly 6250 blocks (1.6M/256): no bounds check.
__global__ __launch_bounds__(256) void norm_kernel(const int* __restrict__ edge,
                                                   const __half* __restrict__ p1h,
                                                   const __half* __restrict__ prh,
                                                   float* __restrict__ out) {
    int e = blockIdx.x * 256 + threadIdx.x;
    int src = edge[e];
    int dst = edge[N_EDGES + e];
    float4 pv = *(const float4*)(p1h + (size_t)src * 8);       // 8 fp16 p1
    float4 qa = *(const float4*)(prh + (size_t)dst * 16);      // 8 fp16 p2
    float4 qb = *(const float4*)(prh + (size_t)dst * 16 + 8);  // 8 bf16 rd
    const __half2* s1p = (const __half2*)&pv;
    const __half2* s2p = (const __half2*)&qa;
    const unsigned short* rdu = (const unsigned short*)&qb;
    floatx4 o0, o1;
    float ov[8];
#pragma unroll
    for (int k = 0; k < 4; ++k) {
        float2 f1 = __half22float2(s1p[k]);
        float2 f2 = __half22float2(s2p[k]);
        ov[2 * k]     = __expf(lrelu(f1.x + f2.x)) * bf2f(rdu[2 * k]);
        ov[2 * k + 1] = __expf(lrelu(f1.y + f2.y)) * bf2f(rdu[2 * k + 1]);
    }
    o0.x = ov[0]; o0.y = ov[1]; o0.z = ov[2]; o0.w = ov[3];
    o1.x = ov[4]; o1.y = ov[5]; o1.z = ov[6]; o1.w = ov[7];
    floatx4* op = (floatx4*)(out + (size_t)e * 8);
    __builtin_nontemporal_store(o0, op);
    __builtin_nontemporal_store(o1, op + 1);
}

extern "C" void kernel_launch(void* const* d_in, const int* in_sizes, int n_in,
                              void* d_out, int out_size, void* d_ws, size_t ws_size,
                              hipStream_t stream) {
    const float* x    = (const float*)d_in[0];
    const float* a    = (const float*)d_in[1];
    const int*   edge = (const int*)d_in[2];
    float* out = (float*)d_out;

    // Workspace layout (~14.5 MB):
    unsigned* sorted = (unsigned*)d_ws;                              // 9.6 MB (NBUCK*CAP)
    __half*   p1h    = (__half*)(sorted + (size_t)NBUCK * CAP);      // 1.6 MB
    __half*   prh    = p1h + NH;                                     // 3.2 MB (p2+rd)
    unsigned* gcur   = (unsigned*)(prh + (size_t)N_NODES * 16);      // 782

    (void)hipMemsetAsync(gcur, 0, NBUCK * sizeof(unsigned), stream);

    proj_scatter_kernel<<<GPROJ + NEB, 1024, 0, stream>>>(x, a, edge, p1h, prh,
                                                          gcur, sorted);
    denom_kernel<<<NBUCK, 512, 0, stream>>>(sorted, gcur, p1h, prh);
    norm_kernel<<<N_EDGES / 256, 256, 0, stream>>>(edge, p1h, prh, out);
}